// Round 2
// baseline (654.892 us; speedup 1.0000x reference)
//
#include <hip/hip_runtime.h>
#include <cstdint>
#include <cstddef>

typedef __attribute__((ext_vector_type(4))) float f32x4;
typedef __attribute__((ext_vector_type(8))) short s16x8;
typedef __attribute__((ext_vector_type(4))) short s16x4;

#define DEV __device__ __forceinline__

DEV short f2bf(float f) {
    unsigned u = __builtin_bit_cast(unsigned, f);
    unsigned r = (u + 0x7FFFu + ((u >> 16) & 1u)) >> 16;
    return (short)r;
}

DEV void gload_lds16(const void* g, void* l) {
    __builtin_amdgcn_global_load_lds(
        (const __attribute__((address_space(1))) unsigned int*)g,
        (__attribute__((address_space(3))) unsigned int*)l, 16, 0, 0);
}

// ---------------- conversion / packing kernels ----------------

__global__ void k_cvt_x(const float* __restrict__ X, short* __restrict__ Xb, int n4) {
    int stride = gridDim.x * blockDim.x;
    for (int i = blockIdx.x * blockDim.x + threadIdx.x; i < n4; i += stride) {
        f32x4 v = *(const f32x4*)&X[i * 4];
        s16x4 s;
#pragma unroll
        for (int j = 0; j < 4; ++j) s[j] = f2bf(v[j]);
        *(s16x4*)&Xb[i * 4] = s;
    }
}

// Wbt[c][d] = W_t[h, d, k]  with c = t*1024 + h*64 + k,  t selects Wq/Wk/Wv
__global__ void k_pack_wqkv(const float* __restrict__ Wq, const float* __restrict__ Wk,
                            const float* __restrict__ Wv, short* __restrict__ Wbt, int n) {
    int stride = gridDim.x * blockDim.x;
    for (int o = blockIdx.x * blockDim.x + threadIdx.x; o < n; o += stride) {
        int c = o >> 10, d = o & 1023;
        int t = c >> 10, h = (c >> 6) & 15, k = c & 63;
        const float* W = (t == 0) ? Wq : (t == 1) ? Wk : Wv;
        Wbt[o] = f2bf(W[(h * 1024 + d) * 64 + k]);
    }
}

// Wobt[n][c] = Wo[c][n]
__global__ void k_pack_wo(const float* __restrict__ Wo, short* __restrict__ Wobt, int n) {
    int stride = gridDim.x * blockDim.x;
    for (int o = blockIdx.x * blockDim.x + threadIdx.x; o < n; o += stride) {
        int nn = o >> 10, c = o & 1023;
        Wobt[o] = f2bf(Wo[c * 1024 + nn]);
    }
}

// ---------------- GEMM: C[M,N] = A[M,1024] * Bt[N,1024]^T ----------------

template <int EPI>
__launch_bounds__(256)
__global__ void gemm_bf16(const short* __restrict__ Ag, const short* __restrict__ Btg,
                          const float* __restrict__ b0, const float* __restrict__ b1,
                          const float* __restrict__ b2,
                          short* __restrict__ O0, short* __restrict__ O1, short* __restrict__ O2,
                          float* __restrict__ Of) {
    __shared__ short As[128 * 64];
    __shared__ short Bs[128 * 64];
    const int tid = threadIdx.x;
    const int wave = tid >> 6, lane = tid & 63;
    const int wm = wave >> 1, wn = wave & 1;
    const int m0 = blockIdx.y * 128, n0 = blockIdx.x * 128;

    f32x4 acc[4][4] = {};

    const int lr = lane >> 3;          // row within 8-row chunk
    const int cb = (lane & 7) * 16;    // linear byte col
    const int cl = cb ^ (lr << 4);     // pre-swizzled source byte col

    for (int kt = 0; kt < 16; ++kt) {
        __syncthreads();
#pragma unroll
        for (int i = 0; i < 4; ++i) {
            int r8 = wave * 32 + i * 8;
            const char* ga = (const char*)(Ag + (size_t)(m0 + r8 + lr) * 1024 + kt * 64) + cl;
            gload_lds16(ga, &As[r8 * 64]);
            const char* gb = (const char*)(Btg + (size_t)(n0 + r8 + lr) * 1024 + kt * 64) + cl;
            gload_lds16(gb, &Bs[r8 * 64]);
        }
        asm volatile("s_waitcnt vmcnt(0)" ::: "memory");
        __syncthreads();
#pragma unroll
        for (int ks = 0; ks < 2; ++ks) {
            int kb = ks * 64 + (lane >> 4) * 16;
            s16x8 af[4], bf[4];
#pragma unroll
            for (int mf = 0; mf < 4; ++mf) {
                int m = wm * 64 + mf * 16 + (lane & 15);
                af[mf] = *(const s16x8*)&As[m * 64 + ((kb ^ ((m & 7) << 4)) >> 1)];
            }
#pragma unroll
            for (int nf = 0; nf < 4; ++nf) {
                int n = wn * 64 + nf * 16 + (lane & 15);
                bf[nf] = *(const s16x8*)&Bs[n * 64 + ((kb ^ ((n & 7) << 4)) >> 1)];
            }
#pragma unroll
            for (int mf = 0; mf < 4; ++mf)
#pragma unroll
                for (int nf = 0; nf < 4; ++nf)
                    acc[mf][nf] = __builtin_amdgcn_mfma_f32_16x16x32_bf16(af[mf], bf[nf],
                                                                          acc[mf][nf], 0, 0, 0);
        }
    }

    if (EPI == 0) {
#pragma unroll
        for (int nf = 0; nf < 4; ++nf) {
            int n = n0 + wn * 64 + nf * 16 + (lane & 15);
            int t = n >> 10;
            int h = (n >> 6) & 15;
            int kk = n & 63;
            const float* bias = (t == 0) ? b0 : (t == 1) ? b1 : b2;
            short* dst = (t == 0) ? O0 : (t == 1) ? O1 : O2;
            float scale = (t == 0) ? 0.125f : 1.0f;
            float bb = bias[h * 64 + kk];
#pragma unroll
            for (int mf = 0; mf < 4; ++mf) {
#pragma unroll
                for (int r = 0; r < 4; ++r) {
                    int m = m0 + wm * 64 + mf * 16 + (lane >> 4) * 4 + r;
                    int b_ = m >> 11, sp = m & 2047;
                    float v = (acc[mf][nf][r] + bb) * scale;
                    dst[(((size_t)(b_ * 16 + h)) * 2048 + sp) * 64 + kk] = f2bf(v);
                }
            }
        }
    } else {
#pragma unroll
        for (int nf = 0; nf < 4; ++nf) {
            int n = n0 + wn * 64 + nf * 16 + (lane & 15);
            float bb = b0[n];
#pragma unroll
            for (int mf = 0; mf < 4; ++mf) {
#pragma unroll
                for (int r = 0; r < 4; ++r) {
                    int m = m0 + wm * 64 + mf * 16 + (lane >> 4) * 4 + r;
                    Of[(size_t)m * 1024 + n] = acc[mf][nf][r] + bb;
                }
            }
        }
    }
}

// ---------------- causal flash attention, paired strips ----------------
// grid (16, 64): block x=i handles q-tiles i (A) and 31-i (B) of head y.
// Uniform work: 33 compute-tiles per block. K/V tiles shared by both strips.
// Double-buffered K/V, one barrier per tile, async V staging (load-early /
// write-late). 4 waves x 16 q-rows per strip.

__launch_bounds__(256, 4)
__global__ void attn_fwd(const short* __restrict__ Qb, const short* __restrict__ Kb,
                         const short* __restrict__ Vb, short* __restrict__ Ab) {
    __shared__ short Ks[2][64 * 64];
    __shared__ short Vt[2][64 * 64];
    __shared__ short Ps[64 * 64];
    const int tid = threadIdx.x, wave = tid >> 6, lane = tid & 63;
    const int bh = blockIdx.y;
    const int qtA = blockIdx.x;        // 0..15 (short strip)
    const int qtB = 31 - qtA;          // 16..31 (long strip)
    const int nt = qtB + 1;
    const size_t base = (size_t)bh * 2048 * 64;
    const float NEG_INF = -__builtin_inff();

    // Q fragments in registers (A-operand layout), both strips
    const int qrow = wave * 16 + (lane & 15);
    const int qoff = (lane >> 4) * 8;
    s16x8 qfA[2], qfB[2];
#pragma unroll
    for (int ks = 0; ks < 2; ++ks) {
        qfA[ks] = *(const s16x8*)&Qb[base + (size_t)(qtA * 64 + qrow) * 64 + ks * 32 + qoff];
        qfB[ks] = *(const s16x8*)&Qb[base + (size_t)(qtB * 64 + qrow) * 64 + ks * 32 + qoff];
    }

    f32x4 oA[4] = {}, oB[4] = {};
    float mA[4], lA[4], mB[4], lB[4];
#pragma unroll
    for (int r = 0; r < 4; ++r) {
        mA[r] = NEG_INF; lA[r] = 0.f; mB[r] = NEG_INF; lB[r] = 0.f;
    }

    const int lr = lane >> 3, cl = ((lane & 7) * 16) ^ (lr << 4);
    const int kp = tid & 31;     // key pair (keys 2kp, 2kp+1)
    const int vb8 = tid >> 5;    // v-block of 8

    auto stageK = [&](int kt, int buf) {
#pragma unroll
        for (int i = 0; i < 2; ++i) {
            int r8 = wave * 16 + i * 8;
            const char* g = (const char*)(Kb + base + (size_t)(kt * 64 + r8 + lr) * 64) + cl;
            gload_lds16(g, &Ks[buf][r8 * 64]);
        }
    };
    auto loadV = [&](int kt, s16x8& v0, s16x8& v1) {
        const short* vsrc = Vb + base + (size_t)(kt * 64 + 2 * kp) * 64 + vb8 * 8;
        v0 = *(const s16x8*)vsrc;
        v1 = *(const s16x8*)(vsrc + 64);
    };
    auto writeV = [&](int buf, const s16x8& v0, const s16x8& v1) {
#pragma unroll
        for (int j = 0; j < 8; ++j) {
            int v = vb8 * 8 + j;
            unsigned pack = (unsigned)(unsigned short)v0[j] |
                            ((unsigned)(unsigned short)v1[j] << 16);
            int byteoff = (4 * kp) ^ ((v & 7) << 4);
            *(unsigned*)((char*)&Vt[buf][v * 64] + byteoff) = pack;
        }
    };

    auto strip_compute = [&](const s16x8* qf, f32x4* o, float* m, float* l,
                             int qt, int kt, int cur) {
        // QK^T: scores[16 q x 64 keys] per wave
        f32x4 sc[4] = {};
#pragma unroll
        for (int ks = 0; ks < 2; ++ks) {
            int kb = ks * 64 + (lane >> 4) * 16;
#pragma unroll
            for (int nf = 0; nf < 4; ++nf) {
                int key = nf * 16 + (lane & 15);
                s16x8 bfr = *(const s16x8*)&Ks[cur][key * 64 + ((kb ^ ((key & 7) << 4)) >> 1)];
                sc[nf] = __builtin_amdgcn_mfma_f32_16x16x32_bf16(qf[ks], bfr, sc[nf], 0, 0, 0);
            }
        }
        if (kt == qt) {  // causal mask on diagonal tile
#pragma unroll
            for (int nf = 0; nf < 4; ++nf) {
                int key = nf * 16 + (lane & 15);
#pragma unroll
                for (int r = 0; r < 4; ++r) {
                    int q = wave * 16 + (lane >> 4) * 4 + r;
                    if (key > q) sc[nf][r] = NEG_INF;
                }
            }
        }
        // online softmax (per q-row; row lives in a 16-lane group)
#pragma unroll
        for (int r = 0; r < 4; ++r) {
            float tm = fmaxf(fmaxf(sc[0][r], sc[1][r]), fmaxf(sc[2][r], sc[3][r]));
#pragma unroll
            for (int off = 1; off < 16; off <<= 1) tm = fmaxf(tm, __shfl_xor(tm, off));
            float mn = fmaxf(m[r], tm);
            float scl = __expf(m[r] - mn);
            float rs = 0.f;
#pragma unroll
            for (int nf = 0; nf < 4; ++nf) {
                float p = __expf(sc[nf][r] - mn);
                sc[nf][r] = p;
                rs += p;
            }
#pragma unroll
            for (int off = 1; off < 16; off <<= 1) rs += __shfl_xor(rs, off);
            l[r] = l[r] * scl + rs;
            m[r] = mn;
#pragma unroll
            for (int nf = 0; nf < 4; ++nf) o[nf][r] *= scl;
            int q = wave * 16 + (lane >> 4) * 4 + r;
#pragma unroll
            for (int nf = 0; nf < 4; ++nf) {
                int keyb = (nf * 16 + (lane & 15)) * 2;
                Ps[q * 64 + ((keyb ^ ((q & 7) << 4)) >> 1)] = f2bf(sc[nf][r]);
            }
        }
        // PV: o += P[16x64] * V[64x64]
#pragma unroll
        for (int ks = 0; ks < 2; ++ks) {
            int q = wave * 16 + (lane & 15);
            int kb = ks * 64 + (lane >> 4) * 16;
            s16x8 pa = *(const s16x8*)&Ps[q * 64 + ((kb ^ ((q & 7) << 4)) >> 1)];
#pragma unroll
            for (int nf = 0; nf < 4; ++nf) {
                int v = nf * 16 + (lane & 15);
                s16x8 vfr = *(const s16x8*)&Vt[cur][v * 64 + ((kb ^ ((v & 7) << 4)) >> 1)];
                o[nf] = __builtin_amdgcn_mfma_f32_16x16x32_bf16(pa, vfr, o[nf], 0, 0, 0);
            }
        }
    };

    // prologue: stage tile 0 into buf 0
    {
        stageK(0, 0);
        s16x8 v0, v1;
        loadV(0, v0, v1);
        writeV(0, v0, v1);
        asm volatile("s_waitcnt vmcnt(0)" ::: "memory");
        __syncthreads();
    }

    for (int kt = 0; kt < nt; ++kt) {
        const int cur = kt & 1, nxt = cur ^ 1;
        const bool pf = (kt + 1 < nt);
        s16x8 v0, v1;
        if (pf) {
            stageK(kt + 1, nxt);
            loadV(kt + 1, v0, v1);
        }
        strip_compute(qfB, oB, mB, lB, qtB, kt, cur);
        if (kt <= qtA) strip_compute(qfA, oA, mA, lA, qtA, kt, cur);
        if (pf) writeV(nxt, v0, v1);
        asm volatile("s_waitcnt vmcnt(0)" ::: "memory");
        __syncthreads();
    }

    // epilogue: A[b, s, h*64+v] bf16
    const int b_ = bh >> 4, h = bh & 15;
#pragma unroll
    for (int nf = 0; nf < 4; ++nf) {
#pragma unroll
        for (int r = 0; r < 4; ++r) {
            int qr = wave * 16 + (lane >> 4) * 4 + r;
            int col = h * 64 + nf * 16 + (lane & 15);
            float va = oA[nf][r] / lA[r];
            Ab[((size_t)(b_ * 2048 + qtA * 64 + qr)) * 1024 + col] = f2bf(va);
            float vb = oB[nf][r] / lB[r];
            Ab[((size_t)(b_ * 2048 + qtB * 64 + qr)) * 1024 + col] = f2bf(vb);
        }
    }
}

// ---------------- launcher ----------------

extern "C" void kernel_launch(void* const* d_in, const int* in_sizes, int n_in,
                              void* d_out, int out_size, void* d_ws, size_t ws_size,
                              hipStream_t stream) {
    const float* X  = (const float*)d_in[0];
    const float* Wq = (const float*)d_in[1];
    const float* bq = (const float*)d_in[2];
    const float* Wk = (const float*)d_in[3];
    const float* bk = (const float*)d_in[4];
    const float* Wv = (const float*)d_in[5];
    const float* bv = (const float*)d_in[6];
    const float* Wo = (const float*)d_in[7];
    const float* bo = (const float*)d_in[8];
    float* out = (float*)d_out;
    char* ws = (char*)d_ws;

    short* Xb   = (short*)(ws);                 // 16 MB
    short* Wbt  = (short*)(ws + 16777216);      // 6 MB
    short* Wobt = (short*)(ws + 23068672);      // 2 MB
    short* Qb   = (short*)(ws + 25165824);      // 16 MB
    short* Kb   = (short*)(ws + 41943040);      // 16 MB
    short* Vb   = (short*)(ws + 58720256);      // 16 MB
    short* Ab   = (short*)(ws + 75497472);      // 16 MB  (total ~88 MB)

    k_cvt_x<<<2048, 256, 0, stream>>>(X, Xb, 8192 * 1024 / 4);
    k_pack_wqkv<<<2048, 256, 0, stream>>>(Wq, Wk, Wv, Wbt, 3 * 1024 * 1024);
    k_pack_wo<<<1024, 256, 0, stream>>>(Wo, Wobt, 1024 * 1024);

    gemm_bf16<0><<<dim3(24, 64), 256, 0, stream>>>(Xb, Wbt, bq, bk, bv, Qb, Kb, Vb, nullptr);
    attn_fwd<<<dim3(16, 64), 256, 0, stream>>>(Qb, Kb, Vb, Ab);
    gemm_bf16<1><<<dim3(8, 64), 256, 0, stream>>>(Ab, Wobt, bo, nullptr, nullptr,
                                                  nullptr, nullptr, nullptr, out);
}

// Round 3
// 552.854 us; speedup vs baseline: 1.1846x; 1.1846x over previous
//
#include <hip/hip_runtime.h>
#include <cstdint>
#include <cstddef>

typedef __attribute__((ext_vector_type(4))) float f32x4;
typedef __attribute__((ext_vector_type(8))) short s16x8;
typedef __attribute__((ext_vector_type(4))) short s16x4;

#define DEV __device__ __forceinline__

DEV short f2bf(float f) {
    unsigned u = __builtin_bit_cast(unsigned, f);
    unsigned r = (u + 0x7FFFu + ((u >> 16) & 1u)) >> 16;
    return (short)r;
}

DEV void gload_lds16(const void* g, void* l) {
    __builtin_amdgcn_global_load_lds(
        (const __attribute__((address_space(1))) unsigned int*)g,
        (__attribute__((address_space(3))) unsigned int*)l, 16, 0, 0);
}

// ---------------- conversion / packing kernels ----------------

__global__ void k_cvt_x(const float* __restrict__ X, short* __restrict__ Xb, int n4) {
    int stride = gridDim.x * blockDim.x;
    for (int i = blockIdx.x * blockDim.x + threadIdx.x; i < n4; i += stride) {
        f32x4 v = *(const f32x4*)&X[i * 4];
        s16x4 s;
#pragma unroll
        for (int j = 0; j < 4; ++j) s[j] = f2bf(v[j]);
        *(s16x4*)&Xb[i * 4] = s;
    }
}

// Wbt[c][d] = W_t[h, d, k]  with c = t*1024 + h*64 + k,  t selects Wq/Wk/Wv
__global__ void k_pack_wqkv(const float* __restrict__ Wq, const float* __restrict__ Wk,
                            const float* __restrict__ Wv, short* __restrict__ Wbt, int n) {
    int stride = gridDim.x * blockDim.x;
    for (int o = blockIdx.x * blockDim.x + threadIdx.x; o < n; o += stride) {
        int c = o >> 10, d = o & 1023;
        int t = c >> 10, h = (c >> 6) & 15, k = c & 63;
        const float* W = (t == 0) ? Wq : (t == 1) ? Wk : Wv;
        Wbt[o] = f2bf(W[(h * 1024 + d) * 64 + k]);
    }
}

// Wobt[n][c] = Wo[c][n]
__global__ void k_pack_wo(const float* __restrict__ Wo, short* __restrict__ Wobt, int n) {
    int stride = gridDim.x * blockDim.x;
    for (int o = blockIdx.x * blockDim.x + threadIdx.x; o < n; o += stride) {
        int nn = o >> 10, c = o & 1023;
        Wobt[o] = f2bf(Wo[c * 1024 + nn]);
    }
}

// ---------------- GEMM: C[M,N] = A[M,1024] * Bt[N,1024]^T ----------------

template <int EPI>
__launch_bounds__(256)
__global__ void gemm_bf16(const short* __restrict__ Ag, const short* __restrict__ Btg,
                          const float* __restrict__ b0, const float* __restrict__ b1,
                          const float* __restrict__ b2,
                          short* __restrict__ O0, short* __restrict__ O1, short* __restrict__ O2,
                          float* __restrict__ Of) {
    __shared__ short As[128 * 64];
    __shared__ short Bs[128 * 64];
    const int tid = threadIdx.x;
    const int wave = tid >> 6, lane = tid & 63;
    const int wm = wave >> 1, wn = wave & 1;
    const int m0 = blockIdx.y * 128, n0 = blockIdx.x * 128;

    f32x4 acc[4][4] = {};

    const int lr = lane >> 3;          // row within 8-row chunk
    const int cb = (lane & 7) * 16;    // linear byte col
    const int cl = cb ^ (lr << 4);     // pre-swizzled source byte col

    for (int kt = 0; kt < 16; ++kt) {
        __syncthreads();
#pragma unroll
        for (int i = 0; i < 4; ++i) {
            int r8 = wave * 32 + i * 8;
            const char* ga = (const char*)(Ag + (size_t)(m0 + r8 + lr) * 1024 + kt * 64) + cl;
            gload_lds16(ga, &As[r8 * 64]);
            const char* gb = (const char*)(Btg + (size_t)(n0 + r8 + lr) * 1024 + kt * 64) + cl;
            gload_lds16(gb, &Bs[r8 * 64]);
        }
        asm volatile("s_waitcnt vmcnt(0)" ::: "memory");
        __syncthreads();
#pragma unroll
        for (int ks = 0; ks < 2; ++ks) {
            int kb = ks * 64 + (lane >> 4) * 16;
            s16x8 af[4], bf[4];
#pragma unroll
            for (int mf = 0; mf < 4; ++mf) {
                int m = wm * 64 + mf * 16 + (lane & 15);
                af[mf] = *(const s16x8*)&As[m * 64 + ((kb ^ ((m & 7) << 4)) >> 1)];
            }
#pragma unroll
            for (int nf = 0; nf < 4; ++nf) {
                int n = wn * 64 + nf * 16 + (lane & 15);
                bf[nf] = *(const s16x8*)&Bs[n * 64 + ((kb ^ ((n & 7) << 4)) >> 1)];
            }
#pragma unroll
            for (int mf = 0; mf < 4; ++mf)
#pragma unroll
                for (int nf = 0; nf < 4; ++nf)
                    acc[mf][nf] = __builtin_amdgcn_mfma_f32_16x16x32_bf16(af[mf], bf[nf],
                                                                          acc[mf][nf], 0, 0, 0);
        }
    }

    if (EPI == 0) {
#pragma unroll
        for (int nf = 0; nf < 4; ++nf) {
            int n = n0 + wn * 64 + nf * 16 + (lane & 15);
            int t = n >> 10;
            int h = (n >> 6) & 15;
            int kk = n & 63;
            const float* bias = (t == 0) ? b0 : (t == 1) ? b1 : b2;
            short* dst = (t == 0) ? O0 : (t == 1) ? O1 : O2;
            float scale = (t == 0) ? 0.125f : 1.0f;
            float bb = bias[h * 64 + kk];
#pragma unroll
            for (int mf = 0; mf < 4; ++mf) {
#pragma unroll
                for (int r = 0; r < 4; ++r) {
                    int m = m0 + wm * 64 + mf * 16 + (lane >> 4) * 4 + r;
                    int b_ = m >> 11, sp = m & 2047;
                    float v = (acc[mf][nf][r] + bb) * scale;
                    dst[(((size_t)(b_ * 16 + h)) * 2048 + sp) * 64 + kk] = f2bf(v);
                }
            }
        }
    } else {
#pragma unroll
        for (int nf = 0; nf < 4; ++nf) {
            int n = n0 + wn * 64 + nf * 16 + (lane & 15);
            float bb = b0[n];
#pragma unroll
            for (int mf = 0; mf < 4; ++mf) {
#pragma unroll
                for (int r = 0; r < 4; ++r) {
                    int m = m0 + wm * 64 + mf * 16 + (lane >> 4) * 4 + r;
                    Of[(size_t)m * 1024 + n] = acc[mf][nf][r] + bb;
                }
            }
        }
    }
}

// ---------------- causal flash attention, paired strips ----------------
// grid (16, 64): block x=i handles q-tiles i (A) and 31-i (B) of head y.
// Uniform work: 33 compute-tiles per block. K/V tiles shared by both strips.
// Double-buffered K/V, one barrier per tile, async V staging (load-early /
// write-late). 4 waves x 16 q-rows per strip.
// ALL per-strip state in named local arrays accessed only with compile-time
// indices; compute bodies are MACROS (round-2 lambda/pointer version sent
// everything to scratch: 1.9 GB of HBM spill traffic).

#define STAGE_K(KT, BUF) do {                                                   \
    _Pragma("unroll")                                                           \
    for (int i_ = 0; i_ < 2; ++i_) {                                            \
        int r8_ = wave * 16 + i_ * 8;                                           \
        const char* g_ = (const char*)(Kb + base + (size_t)((KT) * 64 + r8_ + lr) * 64) + cl; \
        gload_lds16(g_, &Ks[BUF][r8_ * 64]);                                    \
    } } while (0)

#define LOAD_V(KT) do {                                                         \
    const short* vs_ = Vb + base + (size_t)((KT) * 64 + 2 * kp) * 64 + vb8 * 8; \
    v0 = *(const s16x8*)vs_;                                                    \
    v1 = *(const s16x8*)(vs_ + 64); } while (0)

#define WRITE_V(BUF) do {                                                       \
    _Pragma("unroll")                                                           \
    for (int j_ = 0; j_ < 8; ++j_) {                                            \
        int v_ = vb8 * 8 + j_;                                                  \
        unsigned pk_ = (unsigned)(unsigned short)v0[j_] |                       \
                       ((unsigned)(unsigned short)v1[j_] << 16);                \
        int bo_ = (4 * kp) ^ ((v_ & 7) << 4);                                   \
        *(unsigned*)((char*)&Vt[BUF][v_ * 64] + bo_) = pk_;                     \
    } } while (0)

#define STRIP_COMPUTE(QF, O, M, L, QT, KT, CUR) do {                            \
    f32x4 sc_[4] = {};                                                          \
    _Pragma("unroll")                                                           \
    for (int ks_ = 0; ks_ < 2; ++ks_) {                                         \
        int kb_ = ks_ * 64 + (lane >> 4) * 16;                                  \
        _Pragma("unroll")                                                       \
        for (int nf_ = 0; nf_ < 4; ++nf_) {                                     \
            int key_ = nf_ * 16 + (lane & 15);                                  \
            s16x8 bf_ = *(const s16x8*)&Ks[CUR][key_ * 64 + ((kb_ ^ ((key_ & 7) << 4)) >> 1)]; \
            sc_[nf_] = __builtin_amdgcn_mfma_f32_16x16x32_bf16(QF[ks_], bf_, sc_[nf_], 0, 0, 0); \
        }                                                                       \
    }                                                                           \
    if ((KT) == (QT)) {                                                         \
        _Pragma("unroll")                                                       \
        for (int nf_ = 0; nf_ < 4; ++nf_) {                                     \
            int key_ = nf_ * 16 + (lane & 15);                                  \
            _Pragma("unroll")                                                   \
            for (int r_ = 0; r_ < 4; ++r_) {                                    \
                int q_ = wave * 16 + (lane >> 4) * 4 + r_;                      \
                if (key_ > q_) sc_[nf_][r_] = NEG_INF;                          \
            }                                                                   \
        }                                                                       \
    }                                                                           \
    _Pragma("unroll")                                                           \
    for (int r_ = 0; r_ < 4; ++r_) {                                            \
        float tm_ = fmaxf(fmaxf(sc_[0][r_], sc_[1][r_]), fmaxf(sc_[2][r_], sc_[3][r_])); \
        _Pragma("unroll")                                                       \
        for (int of_ = 1; of_ < 16; of_ <<= 1) tm_ = fmaxf(tm_, __shfl_xor(tm_, of_)); \
        float mn_ = fmaxf(M[r_], tm_);                                          \
        float scl_ = __expf(M[r_] - mn_);                                       \
        float rs_ = 0.f;                                                        \
        _Pragma("unroll")                                                       \
        for (int nf_ = 0; nf_ < 4; ++nf_) {                                     \
            float p_ = __expf(sc_[nf_][r_] - mn_);                              \
            sc_[nf_][r_] = p_;                                                  \
            rs_ += p_;                                                          \
        }                                                                       \
        _Pragma("unroll")                                                       \
        for (int of_ = 1; of_ < 16; of_ <<= 1) rs_ += __shfl_xor(rs_, of_);     \
        L[r_] = L[r_] * scl_ + rs_;                                             \
        M[r_] = mn_;                                                            \
        _Pragma("unroll")                                                       \
        for (int nf_ = 0; nf_ < 4; ++nf_) O[nf_][r_] *= scl_;                   \
        int q_ = wave * 16 + (lane >> 4) * 4 + r_;                              \
        _Pragma("unroll")                                                       \
        for (int nf_ = 0; nf_ < 4; ++nf_) {                                     \
            int kb2_ = (nf_ * 16 + (lane & 15)) * 2;                            \
            Ps[q_ * 64 + ((kb2_ ^ ((q_ & 7) << 4)) >> 1)] = f2bf(sc_[nf_][r_]); \
        }                                                                       \
    }                                                                           \
    _Pragma("unroll")                                                           \
    for (int ks_ = 0; ks_ < 2; ++ks_) {                                         \
        int q_ = wave * 16 + (lane & 15);                                       \
        int kb_ = ks_ * 64 + (lane >> 4) * 16;                                  \
        s16x8 pa_ = *(const s16x8*)&Ps[q_ * 64 + ((kb_ ^ ((q_ & 7) << 4)) >> 1)]; \
        _Pragma("unroll")                                                       \
        for (int nf_ = 0; nf_ < 4; ++nf_) {                                     \
            int v_ = nf_ * 16 + (lane & 15);                                    \
            s16x8 vf_ = *(const s16x8*)&Vt[CUR][v_ * 64 + ((kb_ ^ ((v_ & 7) << 4)) >> 1)]; \
            O[nf_] = __builtin_amdgcn_mfma_f32_16x16x32_bf16(pa_, vf_, O[nf_], 0, 0, 0); \
        }                                                                       \
    } } while (0)

__launch_bounds__(256, 4)
__global__ void attn_fwd(const short* __restrict__ Qb, const short* __restrict__ Kb,
                         const short* __restrict__ Vb, short* __restrict__ Ab) {
    __shared__ short Ks[2][64 * 64];
    __shared__ short Vt[2][64 * 64];
    __shared__ short Ps[64 * 64];
    const int tid = threadIdx.x, wave = tid >> 6, lane = tid & 63;
    const int bh = blockIdx.y;
    const int qtA = blockIdx.x;        // 0..15 (short strip)
    const int qtB = 31 - qtA;          // 16..31 (long strip)
    const int nt = qtB + 1;
    const size_t base = (size_t)bh * 2048 * 64;
    const float NEG_INF = -__builtin_inff();

    // Q fragments in registers (A-operand layout), both strips
    const int qrow = wave * 16 + (lane & 15);
    const int qoff = (lane >> 4) * 8;
    s16x8 qfA[2], qfB[2];
#pragma unroll
    for (int ks = 0; ks < 2; ++ks) {
        qfA[ks] = *(const s16x8*)&Qb[base + (size_t)(qtA * 64 + qrow) * 64 + ks * 32 + qoff];
        qfB[ks] = *(const s16x8*)&Qb[base + (size_t)(qtB * 64 + qrow) * 64 + ks * 32 + qoff];
    }

    f32x4 oA[4] = {}, oB[4] = {};
    float mA[4], lA[4], mB[4], lB[4];
#pragma unroll
    for (int r = 0; r < 4; ++r) {
        mA[r] = NEG_INF; lA[r] = 0.f; mB[r] = NEG_INF; lB[r] = 0.f;
    }

    const int lr = lane >> 3, cl = ((lane & 7) * 16) ^ (lr << 4);
    const int kp = tid & 31;     // key pair (keys 2kp, 2kp+1)
    const int vb8 = tid >> 5;    // v-block of 8
    s16x8 v0, v1;

    // prologue: stage tile 0 into buf 0
    STAGE_K(0, 0);
    LOAD_V(0);
    WRITE_V(0);
    asm volatile("s_waitcnt vmcnt(0)" ::: "memory");
    __syncthreads();

    for (int kt = 0; kt < nt; ++kt) {
        const int cur = kt & 1, nxt = cur ^ 1;
        const bool pf = (kt + 1 < nt);
        if (pf) {
            if (nxt) { STAGE_K(kt + 1, 1); } else { STAGE_K(kt + 1, 0); }
            LOAD_V(kt + 1);
        }
        if (cur) {
            STRIP_COMPUTE(qfB, oB, mB, lB, qtB, kt, 1);
            if (kt <= qtA) STRIP_COMPUTE(qfA, oA, mA, lA, qtA, kt, 1);
        } else {
            STRIP_COMPUTE(qfB, oB, mB, lB, qtB, kt, 0);
            if (kt <= qtA) STRIP_COMPUTE(qfA, oA, mA, lA, qtA, kt, 0);
        }
        if (pf) {
            if (nxt) { WRITE_V(1); } else { WRITE_V(0); }
        }
        asm volatile("s_waitcnt vmcnt(0)" ::: "memory");
        __syncthreads();
    }

    // epilogue: A[b, s, h*64+v] bf16
    const int b_ = bh >> 4, h = bh & 15;
#pragma unroll
    for (int nf = 0; nf < 4; ++nf) {
#pragma unroll
        for (int r = 0; r < 4; ++r) {
            int qr = wave * 16 + (lane >> 4) * 4 + r;
            int col = h * 64 + nf * 16 + (lane & 15);
            float va = oA[nf][r] / lA[r];
            Ab[((size_t)(b_ * 2048 + qtA * 64 + qr)) * 1024 + col] = f2bf(va);
            float vb = oB[nf][r] / lB[r];
            Ab[((size_t)(b_ * 2048 + qtB * 64 + qr)) * 1024 + col] = f2bf(vb);
        }
    }
}

// ---------------- launcher ----------------

extern "C" void kernel_launch(void* const* d_in, const int* in_sizes, int n_in,
                              void* d_out, int out_size, void* d_ws, size_t ws_size,
                              hipStream_t stream) {
    const float* X  = (const float*)d_in[0];
    const float* Wq = (const float*)d_in[1];
    const float* bq = (const float*)d_in[2];
    const float* Wk = (const float*)d_in[3];
    const float* bk = (const float*)d_in[4];
    const float* Wv = (const float*)d_in[5];
    const float* bv = (const float*)d_in[6];
    const float* Wo = (const float*)d_in[7];
    const float* bo = (const float*)d_in[8];
    float* out = (float*)d_out;
    char* ws = (char*)d_ws;

    short* Xb   = (short*)(ws);                 // 16 MB
    short* Wbt  = (short*)(ws + 16777216);      // 6 MB
    short* Wobt = (short*)(ws + 23068672);      // 2 MB
    short* Qb   = (short*)(ws + 25165824);      // 16 MB
    short* Kb   = (short*)(ws + 41943040);      // 16 MB
    short* Vb   = (short*)(ws + 58720256);      // 16 MB
    short* Ab   = (short*)(ws + 75497472);      // 16 MB  (total ~88 MB)

    k_cvt_x<<<2048, 256, 0, stream>>>(X, Xb, 8192 * 1024 / 4);
    k_pack_wqkv<<<2048, 256, 0, stream>>>(Wq, Wk, Wv, Wbt, 3 * 1024 * 1024);
    k_pack_wo<<<1024, 256, 0, stream>>>(Wo, Wobt, 1024 * 1024);

    gemm_bf16<0><<<dim3(24, 64), 256, 0, stream>>>(Xb, Wbt, bq, bk, bv, Qb, Kb, Vb, nullptr);
    attn_fwd<<<dim3(16, 64), 256, 0, stream>>>(Qb, Kb, Vb, Ab);
    gemm_bf16<1><<<dim3(8, 64), 256, 0, stream>>>(Ab, Wobt, bo, nullptr, nullptr,
                                                  nullptr, nullptr, nullptr, out);
}

// Round 4
// 273.519 us; speedup vs baseline: 2.3943x; 2.0213x over previous
//
#include <hip/hip_runtime.h>
#include <cstdint>
#include <cstddef>

typedef __attribute__((ext_vector_type(4))) float f32x4;
typedef __attribute__((ext_vector_type(8))) short s16x8;
typedef __attribute__((ext_vector_type(4))) short s16x4;

#define DEV __device__ __forceinline__

DEV short f2bf(float f) {
    unsigned u = __builtin_bit_cast(unsigned, f);
    unsigned r = (u + 0x7FFFu + ((u >> 16) & 1u)) >> 16;
    return (short)r;
}

DEV void gload_lds16(const void* g, void* l) {
    __builtin_amdgcn_global_load_lds(
        (const __attribute__((address_space(1))) unsigned int*)g,
        (__attribute__((address_space(3))) unsigned int*)l, 16, 0, 0);
}

// ---------------- conversion / packing kernels ----------------

__global__ void k_cvt_x(const float* __restrict__ X, short* __restrict__ Xb, int n4) {
    int stride = gridDim.x * blockDim.x;
    for (int i = blockIdx.x * blockDim.x + threadIdx.x; i < n4; i += stride) {
        f32x4 v = *(const f32x4*)&X[i * 4];
        s16x4 s;
#pragma unroll
        for (int j = 0; j < 4; ++j) s[j] = f2bf(v[j]);
        *(s16x4*)&Xb[i * 4] = s;
    }
}

// Wbt[c][d] = W_t[h, d, k]  with c = t*1024 + h*64 + k,  t selects Wq/Wk/Wv
__global__ void k_pack_wqkv(const float* __restrict__ Wq, const float* __restrict__ Wk,
                            const float* __restrict__ Wv, short* __restrict__ Wbt, int n) {
    int stride = gridDim.x * blockDim.x;
    for (int o = blockIdx.x * blockDim.x + threadIdx.x; o < n; o += stride) {
        int c = o >> 10, d = o & 1023;
        int t = c >> 10, h = (c >> 6) & 15, k = c & 63;
        const float* W = (t == 0) ? Wq : (t == 1) ? Wk : Wv;
        Wbt[o] = f2bf(W[(h * 1024 + d) * 64 + k]);
    }
}

// Wobt[n][c] = Wo[c][n]
__global__ void k_pack_wo(const float* __restrict__ Wo, short* __restrict__ Wobt, int n) {
    int stride = gridDim.x * blockDim.x;
    for (int o = blockIdx.x * blockDim.x + threadIdx.x; o < n; o += stride) {
        int nn = o >> 10, c = o & 1023;
        Wobt[o] = f2bf(Wo[c * 1024 + nn]);
    }
}

// ---------------- GEMM: C[M,N] = A[M,1024] * Bt[N,1024]^T ----------------

template <int EPI>
__launch_bounds__(256)
__global__ void gemm_bf16(const short* __restrict__ Ag, const short* __restrict__ Btg,
                          const float* __restrict__ b0, const float* __restrict__ b1,
                          const float* __restrict__ b2,
                          short* __restrict__ O0, short* __restrict__ O1, short* __restrict__ O2,
                          float* __restrict__ Of) {
    __shared__ short As[128 * 64];
    __shared__ short Bs[128 * 64];
    const int tid = threadIdx.x;
    const int wave = tid >> 6, lane = tid & 63;
    const int wm = wave >> 1, wn = wave & 1;
    const int m0 = blockIdx.y * 128, n0 = blockIdx.x * 128;

    f32x4 acc[4][4] = {};

    const int lr = lane >> 3;          // row within 8-row chunk
    const int cb = (lane & 7) * 16;    // linear byte col
    const int cl = cb ^ (lr << 4);     // pre-swizzled source byte col

    for (int kt = 0; kt < 16; ++kt) {
        __syncthreads();
#pragma unroll
        for (int i = 0; i < 4; ++i) {
            int r8 = wave * 32 + i * 8;
            const char* ga = (const char*)(Ag + (size_t)(m0 + r8 + lr) * 1024 + kt * 64) + cl;
            gload_lds16(ga, &As[r8 * 64]);
            const char* gb = (const char*)(Btg + (size_t)(n0 + r8 + lr) * 1024 + kt * 64) + cl;
            gload_lds16(gb, &Bs[r8 * 64]);
        }
        asm volatile("s_waitcnt vmcnt(0)" ::: "memory");
        __syncthreads();
#pragma unroll
        for (int ks = 0; ks < 2; ++ks) {
            int kb = ks * 64 + (lane >> 4) * 16;
            s16x8 af[4], bf[4];
#pragma unroll
            for (int mf = 0; mf < 4; ++mf) {
                int m = wm * 64 + mf * 16 + (lane & 15);
                af[mf] = *(const s16x8*)&As[m * 64 + ((kb ^ ((m & 7) << 4)) >> 1)];
            }
#pragma unroll
            for (int nf = 0; nf < 4; ++nf) {
                int n = wn * 64 + nf * 16 + (lane & 15);
                bf[nf] = *(const s16x8*)&Bs[n * 64 + ((kb ^ ((n & 7) << 4)) >> 1)];
            }
#pragma unroll
            for (int mf = 0; mf < 4; ++mf)
#pragma unroll
                for (int nf = 0; nf < 4; ++nf)
                    acc[mf][nf] = __builtin_amdgcn_mfma_f32_16x16x32_bf16(af[mf], bf[nf],
                                                                          acc[mf][nf], 0, 0, 0);
        }
    }

    if (EPI == 0) {
#pragma unroll
        for (int nf = 0; nf < 4; ++nf) {
            int n = n0 + wn * 64 + nf * 16 + (lane & 15);
            int t = n >> 10;
            int h = (n >> 6) & 15;
            int kk = n & 63;
            const float* bias = (t == 0) ? b0 : (t == 1) ? b1 : b2;
            short* dst = (t == 0) ? O0 : (t == 1) ? O1 : O2;
            float scale = (t == 0) ? 0.125f : 1.0f;
            float bb = bias[h * 64 + kk];
#pragma unroll
            for (int mf = 0; mf < 4; ++mf) {
#pragma unroll
                for (int r = 0; r < 4; ++r) {
                    int m = m0 + wm * 64 + mf * 16 + (lane >> 4) * 4 + r;
                    int b_ = m >> 11, sp = m & 2047;
                    float v = (acc[mf][nf][r] + bb) * scale;
                    dst[(((size_t)(b_ * 16 + h)) * 2048 + sp) * 64 + kk] = f2bf(v);
                }
            }
        }
    } else {
#pragma unroll
        for (int nf = 0; nf < 4; ++nf) {
            int n = n0 + wn * 64 + nf * 16 + (lane & 15);
            float bb = b0[n];
#pragma unroll
            for (int mf = 0; mf < 4; ++mf) {
#pragma unroll
                for (int r = 0; r < 4; ++r) {
                    int m = m0 + wm * 64 + mf * 16 + (lane >> 4) * 4 + r;
                    Of[(size_t)m * 1024 + n] = acc[mf][nf][r] + bb;
                }
            }
        }
    }
}

// ---------------- causal flash attention, paired strips ----------------
// grid (16, 64): block x=i handles q-tiles i (A) and 31-i (B) of head y.
// Uniform work: 33 compute-tiles per block. K/V tiles shared by both strips.
// Double-buffered K/V, one barrier per tile, async V staging (load-early /
// write-late). 4 waves x 16 q-rows per strip.
// NOTE: __launch_bounds__(256) with NO min-waves arg — (256,4) capped the
// allocator at 128 VGPRs and spilled ~60 regs to scratch (1.9 GB HBM traffic,
// rounds 2-3). State arrays use compile-time indices only (macros, not
// lambdas — lambdas sent state through a stack alloca in round 2).

#define STAGE_K(KT, BUF) do {                                                   \
    _Pragma("unroll")                                                           \
    for (int i_ = 0; i_ < 2; ++i_) {                                            \
        int r8_ = wave * 16 + i_ * 8;                                           \
        const char* g_ = (const char*)(Kb + base + (size_t)((KT) * 64 + r8_ + lr) * 64) + cl; \
        gload_lds16(g_, &Ks[BUF][r8_ * 64]);                                    \
    } } while (0)

#define LOAD_V(KT) do {                                                         \
    const short* vs_ = Vb + base + (size_t)((KT) * 64 + 2 * kp) * 64 + vb8 * 8; \
    v0 = *(const s16x8*)vs_;                                                    \
    v1 = *(const s16x8*)(vs_ + 64); } while (0)

#define WRITE_V(BUF) do {                                                       \
    _Pragma("unroll")                                                           \
    for (int j_ = 0; j_ < 8; ++j_) {                                            \
        int v_ = vb8 * 8 + j_;                                                  \
        unsigned pk_ = (unsigned)(unsigned short)v0[j_] |                       \
                       ((unsigned)(unsigned short)v1[j_] << 16);                \
        int bo_ = (4 * kp) ^ ((v_ & 7) << 4);                                   \
        *(unsigned*)((char*)&Vt[BUF][v_ * 64] + bo_) = pk_;                     \
    } } while (0)

#define STRIP_COMPUTE(QF, O, M, L, QT, KT, CUR) do {                            \
    f32x4 sc_[4] = {};                                                          \
    _Pragma("unroll")                                                           \
    for (int ks_ = 0; ks_ < 2; ++ks_) {                                         \
        int kb_ = ks_ * 64 + (lane >> 4) * 16;                                  \
        _Pragma("unroll")                                                       \
        for (int nf_ = 0; nf_ < 4; ++nf_) {                                     \
            int key_ = nf_ * 16 + (lane & 15);                                  \
            s16x8 bf_ = *(const s16x8*)&Ks[CUR][key_ * 64 + ((kb_ ^ ((key_ & 7) << 4)) >> 1)]; \
            sc_[nf_] = __builtin_amdgcn_mfma_f32_16x16x32_bf16(QF[ks_], bf_, sc_[nf_], 0, 0, 0); \
        }                                                                       \
    }                                                                           \
    if ((KT) == (QT)) {                                                         \
        _Pragma("unroll")                                                       \
        for (int nf_ = 0; nf_ < 4; ++nf_) {                                     \
            int key_ = nf_ * 16 + (lane & 15);                                  \
            _Pragma("unroll")                                                   \
            for (int r_ = 0; r_ < 4; ++r_) {                                    \
                int q_ = wave * 16 + (lane >> 4) * 4 + r_;                      \
                if (key_ > q_) sc_[nf_][r_] = NEG_INF;                          \
            }                                                                   \
        }                                                                       \
    }                                                                           \
    _Pragma("unroll")                                                           \
    for (int r_ = 0; r_ < 4; ++r_) {                                            \
        float tm_ = fmaxf(fmaxf(sc_[0][r_], sc_[1][r_]), fmaxf(sc_[2][r_], sc_[3][r_])); \
        _Pragma("unroll")                                                       \
        for (int of_ = 1; of_ < 16; of_ <<= 1) tm_ = fmaxf(tm_, __shfl_xor(tm_, of_)); \
        float mn_ = fmaxf(M[r_], tm_);                                          \
        float scl_ = __expf(M[r_] - mn_);                                       \
        float rs_ = 0.f;                                                        \
        _Pragma("unroll")                                                       \
        for (int nf_ = 0; nf_ < 4; ++nf_) {                                     \
            float p_ = __expf(sc_[nf_][r_] - mn_);                              \
            sc_[nf_][r_] = p_;                                                  \
            rs_ += p_;                                                          \
        }                                                                       \
        _Pragma("unroll")                                                       \
        for (int of_ = 1; of_ < 16; of_ <<= 1) rs_ += __shfl_xor(rs_, of_);     \
        L[r_] = L[r_] * scl_ + rs_;                                             \
        M[r_] = mn_;                                                            \
        _Pragma("unroll")                                                       \
        for (int nf_ = 0; nf_ < 4; ++nf_) O[nf_][r_] *= scl_;                   \
        int q_ = wave * 16 + (lane >> 4) * 4 + r_;                              \
        _Pragma("unroll")                                                       \
        for (int nf_ = 0; nf_ < 4; ++nf_) {                                     \
            int kb2_ = (nf_ * 16 + (lane & 15)) * 2;                            \
            Ps[q_ * 64 + ((kb2_ ^ ((q_ & 7) << 4)) >> 1)] = f2bf(sc_[nf_][r_]); \
        }                                                                       \
    }                                                                           \
    _Pragma("unroll")                                                           \
    for (int ks_ = 0; ks_ < 2; ++ks_) {                                         \
        int q_ = wave * 16 + (lane & 15);                                       \
        int kb_ = ks_ * 64 + (lane >> 4) * 16;                                  \
        s16x8 pa_ = *(const s16x8*)&Ps[q_ * 64 + ((kb_ ^ ((q_ & 7) << 4)) >> 1)]; \
        _Pragma("unroll")                                                       \
        for (int nf_ = 0; nf_ < 4; ++nf_) {                                     \
            int v_ = nf_ * 16 + (lane & 15);                                    \
            s16x8 vf_ = *(const s16x8*)&Vt[CUR][v_ * 64 + ((kb_ ^ ((v_ & 7) << 4)) >> 1)]; \
            O[nf_] = __builtin_amdgcn_mfma_f32_16x16x32_bf16(pa_, vf_, O[nf_], 0, 0, 0); \
        }                                                                       \
    } } while (0)

__launch_bounds__(256)
__global__ void attn_fwd(const short* __restrict__ Qb, const short* __restrict__ Kb,
                         const short* __restrict__ Vb, short* __restrict__ Ab) {
    __shared__ short Ks[2][64 * 64];
    __shared__ short Vt[2][64 * 64];
    __shared__ short Ps[64 * 64];
    const int tid = threadIdx.x, wave = tid >> 6, lane = tid & 63;
    const int bh = blockIdx.y;
    const int qtA = blockIdx.x;        // 0..15 (short strip)
    const int qtB = 31 - qtA;          // 16..31 (long strip)
    const int nt = qtB + 1;
    const size_t base = (size_t)bh * 2048 * 64;
    const float NEG_INF = -__builtin_inff();

    // Q fragments in registers (A-operand layout), both strips
    const int qrow = wave * 16 + (lane & 15);
    const int qoff = (lane >> 4) * 8;
    s16x8 qfA[2], qfB[2];
#pragma unroll
    for (int ks = 0; ks < 2; ++ks) {
        qfA[ks] = *(const s16x8*)&Qb[base + (size_t)(qtA * 64 + qrow) * 64 + ks * 32 + qoff];
        qfB[ks] = *(const s16x8*)&Qb[base + (size_t)(qtB * 64 + qrow) * 64 + ks * 32 + qoff];
    }

    f32x4 oA[4] = {}, oB[4] = {};
    float mA[4], lA[4], mB[4], lB[4];
#pragma unroll
    for (int r = 0; r < 4; ++r) {
        mA[r] = NEG_INF; lA[r] = 0.f; mB[r] = NEG_INF; lB[r] = 0.f;
    }

    const int lr = lane >> 3, cl = ((lane & 7) * 16) ^ (lr << 4);
    const int kp = tid & 31;     // key pair (keys 2kp, 2kp+1)
    const int vb8 = tid >> 5;    // v-block of 8
    s16x8 v0, v1;

    // prologue: stage tile 0 into buf 0
    STAGE_K(0, 0);
    LOAD_V(0);
    WRITE_V(0);
    asm volatile("s_waitcnt vmcnt(0)" ::: "memory");
    __syncthreads();

    for (int kt = 0; kt < nt; ++kt) {
        const int cur = kt & 1, nxt = cur ^ 1;
        const bool pf = (kt + 1 < nt);
        if (pf) {
            if (nxt) { STAGE_K(kt + 1, 1); } else { STAGE_K(kt + 1, 0); }
            LOAD_V(kt + 1);
        }
        if (cur) {
            STRIP_COMPUTE(qfB, oB, mB, lB, qtB, kt, 1);
            if (kt <= qtA) STRIP_COMPUTE(qfA, oA, mA, lA, qtA, kt, 1);
        } else {
            STRIP_COMPUTE(qfB, oB, mB, lB, qtB, kt, 0);
            if (kt <= qtA) STRIP_COMPUTE(qfA, oA, mA, lA, qtA, kt, 0);
        }
        if (pf) {
            if (nxt) { WRITE_V(1); } else { WRITE_V(0); }
        }
        asm volatile("s_waitcnt vmcnt(0)" ::: "memory");
        __syncthreads();
    }

    // epilogue: A[b, s, h*64+v] bf16
    const int b_ = bh >> 4, h = bh & 15;
#pragma unroll
    for (int nf = 0; nf < 4; ++nf) {
#pragma unroll
        for (int r = 0; r < 4; ++r) {
            int qr = wave * 16 + (lane >> 4) * 4 + r;
            int col = h * 64 + nf * 16 + (lane & 15);
            float va = oA[nf][r] / lA[r];
            Ab[((size_t)(b_ * 2048 + qtA * 64 + qr)) * 1024 + col] = f2bf(va);
            float vb = oB[nf][r] / lB[r];
            Ab[((size_t)(b_ * 2048 + qtB * 64 + qr)) * 1024 + col] = f2bf(vb);
        }
    }
}

// ---------------- launcher ----------------

extern "C" void kernel_launch(void* const* d_in, const int* in_sizes, int n_in,
                              void* d_out, int out_size, void* d_ws, size_t ws_size,
                              hipStream_t stream) {
    const float* X  = (const float*)d_in[0];
    const float* Wq = (const float*)d_in[1];
    const float* bq = (const float*)d_in[2];
    const float* Wk = (const float*)d_in[3];
    const float* bk = (const float*)d_in[4];
    const float* Wv = (const float*)d_in[5];
    const float* bv = (const float*)d_in[6];
    const float* Wo = (const float*)d_in[7];
    const float* bo = (const float*)d_in[8];
    float* out = (float*)d_out;
    char* ws = (char*)d_ws;

    short* Xb   = (short*)(ws);                 // 16 MB
    short* Wbt  = (short*)(ws + 16777216);      // 6 MB
    short* Wobt = (short*)(ws + 23068672);      // 2 MB
    short* Qb   = (short*)(ws + 25165824);      // 16 MB
    short* Kb   = (short*)(ws + 41943040);      // 16 MB
    short* Vb   = (short*)(ws + 58720256);      // 16 MB
    short* Ab   = (short*)(ws + 75497472);      // 16 MB  (total ~88 MB)

    k_cvt_x<<<2048, 256, 0, stream>>>(X, Xb, 8192 * 1024 / 4);
    k_pack_wqkv<<<2048, 256, 0, stream>>>(Wq, Wk, Wv, Wbt, 3 * 1024 * 1024);
    k_pack_wo<<<1024, 256, 0, stream>>>(Wo, Wobt, 1024 * 1024);

    gemm_bf16<0><<<dim3(24, 64), 256, 0, stream>>>(Xb, Wbt, bq, bk, bv, Qb, Kb, Vb, nullptr);
    attn_fwd<<<dim3(16, 64), 256, 0, stream>>>(Qb, Kb, Vb, Ab);
    gemm_bf16<1><<<dim3(8, 64), 256, 0, stream>>>(Ab, Wobt, bo, nullptr, nullptr,
                                                  nullptr, nullptr, nullptr, out);
}

// Round 5
// 231.265 us; speedup vs baseline: 2.8318x; 1.1827x over previous
//
#include <hip/hip_runtime.h>
#include <cstdint>
#include <cstddef>

typedef __attribute__((ext_vector_type(4))) float f32x4;
typedef __attribute__((ext_vector_type(8))) short s16x8;
typedef __attribute__((ext_vector_type(4))) short s16x4;

#define DEV __device__ __forceinline__

DEV short f2bf(float f) {
    unsigned u = __builtin_bit_cast(unsigned, f);
    unsigned r = (u + 0x7FFFu + ((u >> 16) & 1u)) >> 16;
    return (short)r;
}

DEV void gload_lds16(const void* g, void* l) {
    __builtin_amdgcn_global_load_lds(
        (const __attribute__((address_space(1))) unsigned int*)g,
        (__attribute__((address_space(3))) unsigned int*)l, 16, 0, 0);
}

// ---------------- conversion / packing kernels ----------------

__global__ void k_cvt_x(const float* __restrict__ X, short* __restrict__ Xb, int n4) {
    int stride = gridDim.x * blockDim.x;
    for (int i = blockIdx.x * blockDim.x + threadIdx.x; i < n4; i += stride) {
        f32x4 v = *(const f32x4*)&X[i * 4];
        s16x4 s;
#pragma unroll
        for (int j = 0; j < 4; ++j) s[j] = f2bf(v[j]);
        *(s16x4*)&Xb[i * 4] = s;
    }
}

// Wbt[c][d] = W_t[h, d, k]  with c = t*1024 + h*64 + k,  t selects Wq/Wk/Wv
__global__ void k_pack_wqkv(const float* __restrict__ Wq, const float* __restrict__ Wk,
                            const float* __restrict__ Wv, short* __restrict__ Wbt, int n) {
    int stride = gridDim.x * blockDim.x;
    for (int o = blockIdx.x * blockDim.x + threadIdx.x; o < n; o += stride) {
        int c = o >> 10, d = o & 1023;
        int t = c >> 10, h = (c >> 6) & 15, k = c & 63;
        const float* W = (t == 0) ? Wq : (t == 1) ? Wk : Wv;
        Wbt[o] = f2bf(W[(h * 1024 + d) * 64 + k]);
    }
}

// Wobt[n][c] = Wo[c][n]
__global__ void k_pack_wo(const float* __restrict__ Wo, short* __restrict__ Wobt, int n) {
    int stride = gridDim.x * blockDim.x;
    for (int o = blockIdx.x * blockDim.x + threadIdx.x; o < n; o += stride) {
        int nn = o >> 10, c = o & 1023;
        Wobt[o] = f2bf(Wo[c * 1024 + nn]);
    }
}

// ---------------- GEMM: C[M,N] = A[M,1024] * Bt[N,1024]^T ----------------

template <int EPI>
__launch_bounds__(256)
__global__ void gemm_bf16(const short* __restrict__ Ag, const short* __restrict__ Btg,
                          const float* __restrict__ b0, const float* __restrict__ b1,
                          const float* __restrict__ b2,
                          short* __restrict__ O0, short* __restrict__ O1, short* __restrict__ O2,
                          float* __restrict__ Of) {
    __shared__ short As[128 * 64];
    __shared__ short Bs[128 * 64];
    const int tid = threadIdx.x;
    const int wave = tid >> 6, lane = tid & 63;
    const int wm = wave >> 1, wn = wave & 1;
    const int m0 = blockIdx.y * 128, n0 = blockIdx.x * 128;

    f32x4 acc[4][4] = {};

    const int lr = lane >> 3;          // row within 8-row chunk
    const int cb = (lane & 7) * 16;    // linear byte col
    const int cl = cb ^ (lr << 4);     // pre-swizzled source byte col

    for (int kt = 0; kt < 16; ++kt) {
        __syncthreads();
#pragma unroll
        for (int i = 0; i < 4; ++i) {
            int r8 = wave * 32 + i * 8;
            const char* ga = (const char*)(Ag + (size_t)(m0 + r8 + lr) * 1024 + kt * 64) + cl;
            gload_lds16(ga, &As[r8 * 64]);
            const char* gb = (const char*)(Btg + (size_t)(n0 + r8 + lr) * 1024 + kt * 64) + cl;
            gload_lds16(gb, &Bs[r8 * 64]);
        }
        asm volatile("s_waitcnt vmcnt(0)" ::: "memory");
        __syncthreads();
#pragma unroll
        for (int ks = 0; ks < 2; ++ks) {
            int kb = ks * 64 + (lane >> 4) * 16;
            s16x8 af[4], bf[4];
#pragma unroll
            for (int mf = 0; mf < 4; ++mf) {
                int m = wm * 64 + mf * 16 + (lane & 15);
                af[mf] = *(const s16x8*)&As[m * 64 + ((kb ^ ((m & 7) << 4)) >> 1)];
            }
#pragma unroll
            for (int nf = 0; nf < 4; ++nf) {
                int n = wn * 64 + nf * 16 + (lane & 15);
                bf[nf] = *(const s16x8*)&Bs[n * 64 + ((kb ^ ((n & 7) << 4)) >> 1)];
            }
#pragma unroll
            for (int mf = 0; mf < 4; ++mf)
#pragma unroll
                for (int nf = 0; nf < 4; ++nf)
                    acc[mf][nf] = __builtin_amdgcn_mfma_f32_16x16x32_bf16(af[mf], bf[nf],
                                                                          acc[mf][nf], 0, 0, 0);
        }
    }

    if (EPI == 0) {
#pragma unroll
        for (int nf = 0; nf < 4; ++nf) {
            int n = n0 + wn * 64 + nf * 16 + (lane & 15);
            int t = n >> 10;
            int h = (n >> 6) & 15;
            int kk = n & 63;
            const float* bias = (t == 0) ? b0 : (t == 1) ? b1 : b2;
            short* dst = (t == 0) ? O0 : (t == 1) ? O1 : O2;
            float scale = (t == 0) ? 0.125f : 1.0f;
            float bb = bias[h * 64 + kk];
#pragma unroll
            for (int mf = 0; mf < 4; ++mf) {
#pragma unroll
                for (int r = 0; r < 4; ++r) {
                    int m = m0 + wm * 64 + mf * 16 + (lane >> 4) * 4 + r;
                    int b_ = m >> 11, sp = m & 2047;
                    float v = (acc[mf][nf][r] + bb) * scale;
                    dst[(((size_t)(b_ * 16 + h)) * 2048 + sp) * 64 + kk] = f2bf(v);
                }
            }
        }
    } else {
#pragma unroll
        for (int nf = 0; nf < 4; ++nf) {
            int n = n0 + wn * 64 + nf * 16 + (lane & 15);
            float bb = b0[n];
#pragma unroll
            for (int mf = 0; mf < 4; ++mf) {
#pragma unroll
                for (int r = 0; r < 4; ++r) {
                    int m = m0 + wm * 64 + mf * 16 + (lane >> 4) * 4 + r;
                    Of[(size_t)m * 1024 + n] = acc[mf][nf][r] + bb;
                }
            }
        }
    }
}

// ---------------- causal flash attention, paired strips ----------------
// grid (16, 64): block x=i handles q-tiles i (A) and 31-i (B) of head y.
// SWAPPED QK^T (mfma(K,Q)): each lane owns one q-row (q = lane&15), so the
// softmax row-reduce is an in-lane tree + 2 shfl_xor (vs 32 serial shfls in
// the unswapped layout). m/l are per-lane scalars; rescale factors are
// broadcast to the PV C-layout rows via 4 independent shfls.
// __launch_bounds__(256) with NO min-waves arg — (256,4) spilled (rounds 2-3).
// State uses compile-time indices only (macros, not lambdas).

#define STAGE_K(KT, BUF) do {                                                   \
    _Pragma("unroll")                                                           \
    for (int i_ = 0; i_ < 2; ++i_) {                                            \
        int r8_ = wave * 16 + i_ * 8;                                           \
        const char* g_ = (const char*)(Kb + base + (size_t)((KT) * 64 + r8_ + lr) * 64) + cl; \
        gload_lds16(g_, &Ks[BUF][r8_ * 64]);                                    \
    } } while (0)

#define LOAD_V(KT) do {                                                         \
    const short* vs_ = Vb + base + (size_t)((KT) * 64 + 2 * kp) * 64 + vb8 * 8; \
    v0 = *(const s16x8*)vs_;                                                    \
    v1 = *(const s16x8*)(vs_ + 64); } while (0)

#define WRITE_V(BUF) do {                                                       \
    _Pragma("unroll")                                                           \
    for (int j_ = 0; j_ < 8; ++j_) {                                            \
        int v_ = vb8 * 8 + j_;                                                  \
        unsigned pk_ = (unsigned)(unsigned short)v0[j_] |                       \
                       ((unsigned)(unsigned short)v1[j_] << 16);                \
        int bo_ = (4 * kp) ^ ((v_ & 7) << 4);                                   \
        *(unsigned*)((char*)&Vt[BUF][v_ * 64] + bo_) = pk_;                     \
    } } while (0)

// sc_[nf][r] holds S[key = nf*16 + 4*(lane>>4) + r][q = wave*16 + (lane&15)]
#define STRIP_COMPUTE(QF, O, M, L, QT, KT, CUR) do {                            \
    f32x4 sc_[4] = {};                                                          \
    __builtin_amdgcn_s_setprio(1);                                              \
    _Pragma("unroll")                                                           \
    for (int ks_ = 0; ks_ < 2; ++ks_) {                                         \
        int kb_ = ks_ * 64 + (lane >> 4) * 16;                                  \
        _Pragma("unroll")                                                       \
        for (int nf_ = 0; nf_ < 4; ++nf_) {                                     \
            int key_ = nf_ * 16 + (lane & 15);                                  \
            s16x8 bf_ = *(const s16x8*)&Ks[CUR][key_ * 64 + ((kb_ ^ ((key_ & 7) << 4)) >> 1)]; \
            sc_[nf_] = __builtin_amdgcn_mfma_f32_16x16x32_bf16(bf_, QF[ks_], sc_[nf_], 0, 0, 0); \
        }                                                                       \
    }                                                                           \
    __builtin_amdgcn_s_setprio(0);                                              \
    if ((KT) == (QT)) {                                                         \
        int qq_ = wave * 16 + (lane & 15);                                      \
        _Pragma("unroll")                                                       \
        for (int nf_ = 0; nf_ < 4; ++nf_) {                                     \
            _Pragma("unroll")                                                   \
            for (int r_ = 0; r_ < 4; ++r_) {                                    \
                int key_ = nf_ * 16 + (lane >> 4) * 4 + r_;                     \
                if (key_ > qq_) sc_[nf_][r_] = NEG_INF;                         \
            }                                                                   \
        }                                                                       \
    }                                                                           \
    float mnf0_ = fmaxf(fmaxf(sc_[0][0], sc_[0][1]), fmaxf(sc_[0][2], sc_[0][3])); \
    float mnf1_ = fmaxf(fmaxf(sc_[1][0], sc_[1][1]), fmaxf(sc_[1][2], sc_[1][3])); \
    float mnf2_ = fmaxf(fmaxf(sc_[2][0], sc_[2][1]), fmaxf(sc_[2][2], sc_[2][3])); \
    float mnf3_ = fmaxf(fmaxf(sc_[3][0], sc_[3][1]), fmaxf(sc_[3][2], sc_[3][3])); \
    float tm_ = fmaxf(fmaxf(mnf0_, mnf1_), fmaxf(mnf2_, mnf3_));                \
    tm_ = fmaxf(tm_, __shfl_xor(tm_, 16));                                      \
    tm_ = fmaxf(tm_, __shfl_xor(tm_, 32));                                      \
    const bool nos_ = __all(tm_ <= M);                                          \
    float mn_, scl_;                                                            \
    if (nos_) { mn_ = M; scl_ = 1.f; }                                          \
    else { mn_ = fmaxf(M, tm_); scl_ = __expf(M - mn_); M = mn_; }              \
    _Pragma("unroll")                                                           \
    for (int nf_ = 0; nf_ < 4; ++nf_)                                           \
        _Pragma("unroll")                                                       \
        for (int r_ = 0; r_ < 4; ++r_)                                          \
            sc_[nf_][r_] = __expf(sc_[nf_][r_] - mn_);                          \
    float snf0_ = (sc_[0][0] + sc_[0][1]) + (sc_[0][2] + sc_[0][3]);            \
    float snf1_ = (sc_[1][0] + sc_[1][1]) + (sc_[1][2] + sc_[1][3]);            \
    float snf2_ = (sc_[2][0] + sc_[2][1]) + (sc_[2][2] + sc_[2][3]);            \
    float snf3_ = (sc_[3][0] + sc_[3][1]) + (sc_[3][2] + sc_[3][3]);            \
    float rs_ = (snf0_ + snf1_) + (snf2_ + snf3_);                              \
    rs_ += __shfl_xor(rs_, 16);                                                 \
    rs_ += __shfl_xor(rs_, 32);                                                 \
    L = L * scl_ + rs_;                                                         \
    int q_ = wave * 16 + (lane & 15);                                           \
    _Pragma("unroll")                                                           \
    for (int nf_ = 0; nf_ < 4; ++nf_) {                                         \
        s16x4 pk_;                                                              \
        _Pragma("unroll")                                                       \
        for (int r_ = 0; r_ < 4; ++r_) pk_[r_] = f2bf(sc_[nf_][r_]);            \
        int bo_ = (nf_ * 32 + (lane >> 4) * 8) ^ ((q_ & 7) << 4);               \
        *(s16x4*)((char*)&Ps[q_ * 64] + bo_) = pk_;                             \
    }                                                                           \
    if (!nos_) {                                                                \
        _Pragma("unroll")                                                       \
        for (int r_ = 0; r_ < 4; ++r_) {                                        \
            float sclc_ = __shfl(scl_, (lane >> 4) * 4 + r_);                   \
            _Pragma("unroll")                                                   \
            for (int nf_ = 0; nf_ < 4; ++nf_) O[nf_][r_] *= sclc_;              \
        }                                                                       \
    }                                                                           \
    __builtin_amdgcn_s_setprio(1);                                              \
    _Pragma("unroll")                                                           \
    for (int ks_ = 0; ks_ < 2; ++ks_) {                                         \
        int kb_ = ks_ * 64 + (lane >> 4) * 16;                                  \
        s16x8 pa_ = *(const s16x8*)&Ps[q_ * 64 + ((kb_ ^ ((q_ & 7) << 4)) >> 1)]; \
        _Pragma("unroll")                                                       \
        for (int nf_ = 0; nf_ < 4; ++nf_) {                                     \
            int v_ = nf_ * 16 + (lane & 15);                                    \
            s16x8 vf_ = *(const s16x8*)&Vt[CUR][v_ * 64 + ((kb_ ^ ((v_ & 7) << 4)) >> 1)]; \
            O[nf_] = __builtin_amdgcn_mfma_f32_16x16x32_bf16(pa_, vf_, O[nf_], 0, 0, 0); \
        }                                                                       \
    }                                                                           \
    __builtin_amdgcn_s_setprio(0);                                              \
    } while (0)

__launch_bounds__(256)
__global__ void attn_fwd(const short* __restrict__ Qb, const short* __restrict__ Kb,
                         const short* __restrict__ Vb, short* __restrict__ Ab) {
    __shared__ short Ks[2][64 * 64];
    __shared__ short Vt[2][64 * 64];
    __shared__ short Ps[64 * 64];
    const int tid = threadIdx.x, wave = tid >> 6, lane = tid & 63;
    const int bh = blockIdx.y;
    const int qtA = blockIdx.x;        // 0..15 (short strip)
    const int qtB = 31 - qtA;          // 16..31 (long strip)
    const int nt = qtB + 1;
    const size_t base = (size_t)bh * 2048 * 64;
    const float NEG_INF = -__builtin_inff();

    // Q fragments in registers; layout serves as both A- and B-operand
    const int qrow = wave * 16 + (lane & 15);
    const int qoff = (lane >> 4) * 8;
    s16x8 qfA[2], qfB[2];
#pragma unroll
    for (int ks = 0; ks < 2; ++ks) {
        qfA[ks] = *(const s16x8*)&Qb[base + (size_t)(qtA * 64 + qrow) * 64 + ks * 32 + qoff];
        qfB[ks] = *(const s16x8*)&Qb[base + (size_t)(qtB * 64 + qrow) * 64 + ks * 32 + qoff];
    }

    f32x4 oA[4] = {}, oB[4] = {};
    float mA = NEG_INF, lA = 0.f, mB = NEG_INF, lB = 0.f;

    const int lr = lane >> 3, cl = ((lane & 7) * 16) ^ (lr << 4);
    const int kp = tid & 31;     // key pair (keys 2kp, 2kp+1)
    const int vb8 = tid >> 5;    // v-block of 8
    s16x8 v0, v1;

    // prologue: stage tile 0 into buf 0
    STAGE_K(0, 0);
    LOAD_V(0);
    WRITE_V(0);
    asm volatile("s_waitcnt vmcnt(0)" ::: "memory");
    __syncthreads();

    for (int kt = 0; kt < nt; ++kt) {
        const int cur = kt & 1, nxt = cur ^ 1;
        const bool pf = (kt + 1 < nt);
        if (pf) {
            if (nxt) { STAGE_K(kt + 1, 1); } else { STAGE_K(kt + 1, 0); }
            LOAD_V(kt + 1);
        }
        if (cur) {
            STRIP_COMPUTE(qfB, oB, mB, lB, qtB, kt, 1);
            if (kt <= qtA) STRIP_COMPUTE(qfA, oA, mA, lA, qtA, kt, 1);
        } else {
            STRIP_COMPUTE(qfB, oB, mB, lB, qtB, kt, 0);
            if (kt <= qtA) STRIP_COMPUTE(qfA, oA, mA, lA, qtA, kt, 0);
        }
        if (pf) {
            if (nxt) { WRITE_V(1); } else { WRITE_V(0); }
        }
        asm volatile("s_waitcnt vmcnt(0)" ::: "memory");
        __syncthreads();
    }

    // epilogue: A[b, s, h*64+v] bf16  (l broadcast to C-layout rows)
    const int b_ = bh >> 4, h = bh & 15;
#pragma unroll
    for (int r = 0; r < 4; ++r) {
        float lac_ = __shfl(lA, (lane >> 4) * 4 + r);
        float lbc_ = __shfl(lB, (lane >> 4) * 4 + r);
        int qr = wave * 16 + (lane >> 4) * 4 + r;
#pragma unroll
        for (int nf = 0; nf < 4; ++nf) {
            int col = h * 64 + nf * 16 + (lane & 15);
            float va = oA[nf][r] / lac_;
            Ab[((size_t)(b_ * 2048 + qtA * 64 + qr)) * 1024 + col] = f2bf(va);
            float vb = oB[nf][r] / lbc_;
            Ab[((size_t)(b_ * 2048 + qtB * 64 + qr)) * 1024 + col] = f2bf(vb);
        }
    }
}

// ---------------- launcher ----------------

extern "C" void kernel_launch(void* const* d_in, const int* in_sizes, int n_in,
                              void* d_out, int out_size, void* d_ws, size_t ws_size,
                              hipStream_t stream) {
    const float* X  = (const float*)d_in[0];
    const float* Wq = (const float*)d_in[1];
    const float* bq = (const float*)d_in[2];
    const float* Wk = (const float*)d_in[3];
    const float* bk = (const float*)d_in[4];
    const float* Wv = (const float*)d_in[5];
    const float* bv = (const float*)d_in[6];
    const float* Wo = (const float*)d_in[7];
    const float* bo = (const float*)d_in[8];
    float* out = (float*)d_out;
    char* ws = (char*)d_ws;

    short* Xb   = (short*)(ws);                 // 16 MB
    short* Wbt  = (short*)(ws + 16777216);      // 6 MB
    short* Wobt = (short*)(ws + 23068672);      // 2 MB
    short* Qb   = (short*)(ws + 25165824);      // 16 MB
    short* Kb   = (short*)(ws + 41943040);      // 16 MB
    short* Vb   = (short*)(ws + 58720256);      // 16 MB
    short* Ab   = (short*)(ws + 75497472);      // 16 MB  (total ~88 MB)

    k_cvt_x<<<2048, 256, 0, stream>>>(X, Xb, 8192 * 1024 / 4);
    k_pack_wqkv<<<2048, 256, 0, stream>>>(Wq, Wk, Wv, Wbt, 3 * 1024 * 1024);
    k_pack_wo<<<1024, 256, 0, stream>>>(Wo, Wobt, 1024 * 1024);

    gemm_bf16<0><<<dim3(24, 64), 256, 0, stream>>>(Xb, Wbt, bq, bk, bv, Qb, Kb, Vb, nullptr);
    attn_fwd<<<dim3(16, 64), 256, 0, stream>>>(Qb, Kb, Vb, Ab);
    gemm_bf16<1><<<dim3(8, 64), 256, 0, stream>>>(Ab, Wobt, bo, nullptr, nullptr,
                                                  nullptr, nullptr, nullptr, out);
}